// Round 1
// baseline (557.630 us; speedup 1.0000x reference)
//
#include <hip/hip_runtime.h>
#include <stdint.h>

#define NB 32      // batch
#define NC 32      // in channels
#define NN 1024    // nodes
#define NT 12      // time
#define NJ (NB*NC*NT)  // 12288
#define NO 32      // out channels
#define TIN 224    // (2*3+1)*32

typedef __attribute__((ext_vector_type(8))) __bf16 bf16x8;
typedef __attribute__((ext_vector_type(4))) float f32x4;
typedef unsigned short u16;
typedef unsigned int u32;

__device__ __forceinline__ u16 f2bf(float f){
  u32 u = __float_as_uint(f);
  u32 r = (u + 0x7FFFu + ((u >> 16) & 1u)) >> 16;   // RNE
  return (u16)r;
}
__device__ __forceinline__ float bf2f(u16 h){
  return __uint_as_float(((u32)h) << 16);
}

typedef const __attribute__((address_space(1))) u32* gp_t;
typedef __attribute__((address_space(3))) u32* lp_t;
__device__ __forceinline__ void gll16(const void* g, void* l){
  // 16B per lane, LDS dest is wave-uniform base + lane*16
  __builtin_amdgcn_global_load_lds((gp_t)g, (lp_t)l, 16, 0, 0);
}

// ---------- prep adj: At[z][m][n] = bf16(adj_z[n][m]) ----------
__global__ __launch_bounds__(256) void k_prep_adj(const float* __restrict__ a0,
      const float* __restrict__ a1, const float* __restrict__ a2, u16* __restrict__ At){
  __shared__ float tile[32][33];
  const float* A = (blockIdx.z==0) ? a0 : (blockIdx.z==1 ? a1 : a2);
  int n0 = blockIdx.x*32, m0 = blockIdx.y*32;
  int tx = threadIdx.x, ty = threadIdx.y;  // block (32,8)
  #pragma unroll
  for (int r=0;r<4;r++)
    tile[ty + 8*r][tx] = A[(size_t)(n0 + ty + 8*r)*NN + m0 + tx];
  __syncthreads();
  u16* dst = At + (size_t)blockIdx.z*NN*NN;
  #pragma unroll
  for (int r=0;r<4;r++)
    dst[(size_t)(m0 + ty + 8*r)*NN + n0 + tx] = f2bf(tile[tx][ty + 8*r]);
}

// ---------- prep x: Zt[j][n] = bf16(x[p,n,t]), j = p*12+t ----------
__global__ __launch_bounds__(256) void k_prep_x(const float* __restrict__ x, u16* __restrict__ Zt){
  int n = blockIdx.x*256 + threadIdx.x;
  int j = blockIdx.y;
  int p = j / NT, t = j - p*NT;
  Zt[(size_t)j*NN + n] = f2bf(x[(size_t)p*NN*NT + n*NT + t]);
}

// ---------- GEMM: Out[j][m] = sum_k Amat[m][k] * Bmat[j][k] ----------
// Amat [1024][1024] bf16 (K contiguous), Bmat [12288][1024] bf16 (K contiguous)
#define BKK 64
__global__ __launch_bounds__(256) void k_gemm(const u16* __restrict__ Amat,
                                              const u16* __restrict__ Bmat,
                                              u16* __restrict__ Out){
  __shared__ __align__(16) u16 As[128*BKK];   // [m_local][k] 16KB
  __shared__ __align__(16) u16 Bs[128*BKK];   // [j_local][k] 16KB
  int tid = threadIdx.x;
  int w = tid >> 6, lane = tid & 63;
  int m0 = blockIdx.y * 128, j0 = blockIdx.x * 128;
  int wr = w >> 1, wc = w & 1;
  int lrow = lane & 15, kgrp = lane >> 4;
  int lr8 = lane >> 3, lc8 = lane & 7;

  f32x4 acc[4][4];
  #pragma unroll
  for (int i=0;i<4;i++)
    #pragma unroll
    for (int jj=0;jj<4;jj++)
      acc[i][jj] = (f32x4){0.f,0.f,0.f,0.f};

  const u16* Abase = Amat + (size_t)m0*1024;
  const u16* Bbase = Bmat + (size_t)j0*1024;

  for (int kt=0; kt<1024/BKK; ++kt){
    int k0 = kt*BKK;
    #pragma unroll
    for (int i=0;i<4;i++){
      int q = w*4 + i;                 // 16 x 1KB chunks per tile
      int row = q*8 + lr8;             // 8 rows (128B each) per chunk
      gll16(Abase + (size_t)row*1024 + k0 + lc8*8, (u16*)As + q*512);
      gll16(Bbase + (size_t)row*1024 + k0 + lc8*8, (u16*)Bs + q*512);
    }
    __syncthreads();                   // vmcnt(0) drain + barrier: LDS ready
    #pragma unroll
    for (int kk=0; kk<2; ++kk){
      bf16x8 af[4], bfr[4];
      #pragma unroll
      for (int mi=0;mi<4;mi++)
        af[mi] = *reinterpret_cast<const bf16x8*>(&As[(wr*64+mi*16+lrow)*BKK + kk*32 + kgrp*8]);
      #pragma unroll
      for (int ji=0;ji<4;ji++)
        bfr[ji] = *reinterpret_cast<const bf16x8*>(&Bs[(wc*64+ji*16+lrow)*BKK + kk*32 + kgrp*8]);
      #pragma unroll
      for (int mi=0;mi<4;mi++)
        #pragma unroll
        for (int ji=0;ji<4;ji++)
          acc[mi][ji] = __builtin_amdgcn_mfma_f32_16x16x32_bf16(af[mi], bfr[ji], acc[mi][ji], 0, 0, 0);
    }
    __syncthreads();                   // all reads done before next overwrite
  }

  // epilogue: C/D frag mapping col=lane&15 (j), row=(lane>>4)*4+r (m)
  #pragma unroll
  for (int mi=0;mi<4;mi++){
    #pragma unroll
    for (int ji=0;ji<4;ji++){
      int jg = j0 + wc*64 + ji*16 + lrow;
      int mg = m0 + wr*64 + mi*16 + kgrp*4;
      ushort4 st;
      st.x = f2bf(acc[mi][ji][0]);
      st.y = f2bf(acc[mi][ji][1]);
      st.z = f2bf(acc[mi][ji][2]);
      st.w = f2bf(acc[mi][ji][3]);
      *reinterpret_cast<ushort4*>(&Out[(size_t)jg*1024 + mg]) = st;
    }
  }
}

// ---------- accumulate channel mix into y ----------
// gbase = (1+2g)*32 : columns of W for hop1 of adjacency g; +32 for hop2.
__global__ __launch_bounds__(256) void k_accum(const float* __restrict__ x,
     const u16* __restrict__ H1, const u16* __restrict__ H2,
     const float* __restrict__ W, const float* __restrict__ bias,
     float* __restrict__ y, int gbase, int first){
  int tid = threadIdx.x;
  int n = blockIdx.x*256 + tid;
  int t = blockIdx.y, b = blockIdx.z;
  float h1[NC], h2[NC];
  size_t hbase = ((size_t)b*NC*NT + t)*NN + n;       // j=(b*32+c)*12+t, +c*12*1024
  #pragma unroll
  for (int c=0;c<NC;c++){
    h1[c] = bf2f(H1[hbase + (size_t)c*NT*NN]);
    h2[c] = bf2f(H2[hbase + (size_t)c*NT*NN]);
  }
  if (first){
    float xv[NC];
    #pragma unroll
    for (int c=0;c<NC;c++) xv[c] = x[((size_t)(b*NC+c)*NN + n)*NT + t];
    #pragma unroll
    for (int o=0;o<NO;o++){
      float s = bias[o];
      #pragma unroll
      for (int c=0;c<NC;c++){
        s += W[o*TIN + c]            * xv[c];
        s += W[o*TIN + gbase + c]    * h1[c];
        s += W[o*TIN + gbase + 32 + c] * h2[c];
      }
      y[((size_t)(b*NO+o)*NN + n)*NT + t] = s;
    }
  } else {
    #pragma unroll
    for (int o=0;o<NO;o++){
      float s = y[((size_t)(b*NO+o)*NN + n)*NT + t];
      #pragma unroll
      for (int c=0;c<NC;c++){
        s += W[o*TIN + gbase + c]    * h1[c];
        s += W[o*TIN + gbase + 32 + c] * h2[c];
      }
      y[((size_t)(b*NO+o)*NN + n)*NT + t] = s;
    }
  }
}

extern "C" void kernel_launch(void* const* d_in, const int* in_sizes, int n_in,
                              void* d_out, int out_size, void* d_ws, size_t ws_size,
                              hipStream_t stream){
  const float* x    = (const float*)d_in[0];
  const float* a0   = (const float*)d_in[1];
  const float* a1   = (const float*)d_in[2];
  const float* a2   = (const float*)d_in[3];
  const float* W    = (const float*)d_in[4];
  const float* bias = (const float*)d_in[5];
  float* y = (float*)d_out;

  char* ws = (char*)d_ws;
  u16* At = (u16*)ws;  ws += (size_t)3*NN*NN*2;   // 6 MB  transposed bf16 adjacencies
  u16* Zt = (u16*)ws;  ws += (size_t)NJ*NN*2;     // 25 MB x in [j][n] bf16
  u16* H1 = (u16*)ws;  ws += (size_t)NJ*NN*2;     // 25 MB hop-1
  u16* H2 = (u16*)ws;  ws += (size_t)NJ*NN*2;     // 25 MB hop-2
  (void)ws_size; (void)in_sizes; (void)n_in; (void)out_size;

  k_prep_adj<<<dim3(32,32,3), dim3(32,8), 0, stream>>>(a0, a1, a2, At);
  k_prep_x  <<<dim3(NN/256, NJ), 256, 0, stream>>>(x, Zt);

  for (int g=0; g<3; ++g){
    const u16* Ag = At + (size_t)g*NN*NN;
    k_gemm<<<dim3(NJ/128, NN/128), 256, 0, stream>>>(Ag, Zt, H1);
    k_gemm<<<dim3(NJ/128, NN/128), 256, 0, stream>>>(Ag, H1, H2);
    k_accum<<<dim3(NN/256, NT, NB), 256, 0, stream>>>(x, H1, H2, W, bias, y,
                                                      (1+2*g)*32, g==0 ? 1 : 0);
  }
}